// Round 1
// 2757.120 us; speedup vs baseline: 1.2271x; 1.2271x over previous
//
#include <hip/hip_runtime.h>
#include <math.h>

#define NNODES 50000
#define NEDGES 1600000
#define MP 50048   // 391 * 128, padded row count

typedef unsigned int uint_t;
typedef __attribute__((ext_vector_type(8))) short short8;
typedef __attribute__((ext_vector_type(4))) float f32x4;

__device__ __forceinline__ unsigned short f2bf(float f){
  union { float f; uint_t u; } v; v.f = f;
  uint_t u = v.u;
  uint_t r = (u + 0x7fffu + ((u >> 16) & 1u)) >> 16;   // RNE
  return (unsigned short)r;
}
__device__ __forceinline__ float bf2f(uint_t u){
  union { uint_t u; float f; } v; v.u = u << 16;
  return v.f;
}

// ---------------- CSR build ----------------
__global__ void k_init_counts(int* cnt_d, int* cnt_t, int n){
  int i = blockIdx.x*blockDim.x + threadIdx.x;
  if (i < n){ cnt_d[i] = 0; cnt_t[i] = 0; }
}

__global__ void k_count(const int* __restrict__ ei, int* __restrict__ cnt, int e){
  int i = blockIdx.x*blockDim.x + threadIdx.x;
  if (i < e) atomicAdd(&cnt[ei[e + i]], 1);   // dst row = ei[E + i]
}

// ---- parallel 3-phase exclusive scan (replaces single-block k_scan) ----
// phase 1: per-block (1024 elems) local exclusive scan + block total; dinv
__global__ __launch_bounds__(1024) void k_scan_blk(
    const int* __restrict__ cnt_d, const int* __restrict__ cnt_t,
    int* __restrict__ rp_d, int* __restrict__ rp_t,
    float* __restrict__ dinv_d, float* __restrict__ dinv_t,
    int* __restrict__ bsum, int n)
{
  const int g = blockIdx.y;
  const int* cnt = g ? cnt_t : cnt_d;
  int* rp        = g ? rp_t  : rp_d;
  float* dinv    = g ? dinv_t: dinv_d;
  __shared__ int sdata[1024];
  const int tid = threadIdx.x;
  const int i = blockIdx.x*1024 + tid;
  int v = (i < n) ? cnt[i] : 0;
  sdata[tid] = v;
  __syncthreads();
  for (int off = 1; off < 1024; off <<= 1){
    int t = (tid >= off) ? sdata[tid - off] : 0;
    __syncthreads();
    sdata[tid] += t;
    __syncthreads();
  }
  if (i < n){
    rp[i]   = sdata[tid] - v;                 // block-local exclusive
    dinv[i] = 1.0f / sqrtf(1.0f + (float)v);
  }
  if (tid == 1023) bsum[g*64 + blockIdx.x] = sdata[1023];
}

// phase 2: scan block totals (one wave per graph), write rowptr[n]=E total
__global__ __launch_bounds__(128) void k_scan_bsum(
    int* __restrict__ bsum, int* __restrict__ rp_d, int* __restrict__ rp_t,
    int nb, int n)
{
  const int g = threadIdx.x >> 6;
  const int lane = threadIdx.x & 63;
  int orig = (lane < nb) ? bsum[g*64 + lane] : 0;
  int v = orig;
  #pragma unroll
  for (int off = 1; off < 64; off <<= 1){
    int t = __shfl_up(v, off);
    if (lane >= off) v += t;
  }
  if (lane < nb) bsum[g*64 + lane] = v - orig;   // exclusive block offset
  if (lane == nb-1){
    if (g) rp_t[n] = v; else rp_d[n] = v;
  }
}

// phase 3: apply block offsets; also init cur
__global__ __launch_bounds__(1024) void k_scan_add(
    const int* __restrict__ bsum,
    int* __restrict__ rp_d, int* __restrict__ rp_t,
    int* __restrict__ cur_d, int* __restrict__ cur_t, int n)
{
  const int g = blockIdx.y;
  int* rp  = g ? rp_t  : rp_d;
  int* cur = g ? cur_t : cur_d;
  const int i = blockIdx.x*1024 + threadIdx.x;
  if (i < n){
    int v = rp[i] + bsum[g*64 + blockIdx.x];
    rp[i] = v;
    cur[i] = v;
  }
}

__global__ void k_fill(const int* __restrict__ ei, int* __restrict__ cur,
                       int* __restrict__ col, float* __restrict__ w,
                       const float* __restrict__ dinv, int e){
  int i = blockIdx.x*blockDim.x + threadIdx.x;
  if (i < e){
    int src = ei[i], dst = ei[e + i];
    int pos = atomicAdd(&cur[dst], 1);
    col[pos] = src;
    w[pos]   = dinv[src];
  }
}

// ---------------- cast fp32 -> bf16 (flat, zero-pad tail) ----------------
__global__ void k_cast_bf(const float* __restrict__ src, unsigned short* __restrict__ dst,
                          long long n_src, long long n_total){
  long long i = ((long long)blockIdx.x * 256 + threadIdx.x) * 4;
  if (i >= n_total) return;
  ushort4 o;
  if (i < n_src){
    float4 v = *(const float4*)&src[i];
    o.x = f2bf(v.x); o.y = f2bf(v.y); o.z = f2bf(v.z); o.w = f2bf(v.w);
  } else { o.x = 0; o.y = 0; o.z = 0; o.w = 0; }
  *(ushort4*)&dst[i] = o;
}

// ---------------- transpose + cast: W[K,N] fp32 -> WT[N,K] bf16 ----------------
__global__ __launch_bounds__(256) void k_tr_cast(const float* __restrict__ W,
    unsigned short* __restrict__ WT, int K, int N){
  __shared__ float t[32][33];
  int bx = blockIdx.x * 32;   // N dim
  int by = blockIdx.y * 32;   // K dim
  int x = threadIdx.x & 31, y0 = threadIdx.x >> 5;
  for (int y = y0; y < 32; y += 8)
    t[y][x] = W[(size_t)(by + y)*N + bx + x];
  __syncthreads();
  for (int y = y0; y < 32; y += 8)
    WT[(size_t)(bx + y)*K + by + x] = f2bf(t[x][y]);
}

// ---------------- bf16 MFMA GEMM: C[M,N] = A[M,K] @ BT[N,K]^T ----------------
// 128x128 block tile, BK=32, 256 threads (4 waves), 4x4 16x16x32 MFMA per wave.
// global_load_lds width=16 staging; XOR swizzle keeps ds_read_b128 conflicts <=2-way.
// XCD-aware bijective chunked block swizzle (T1): each XCD owns a contiguous
// row-panel chunk so A panels are fetched once per XCD instead of 8x.
__global__ __launch_bounds__(256) void gemm_bf16(
    const unsigned short* __restrict__ A, const unsigned short* __restrict__ BT,
    const float* __restrict__ bias, void* __restrict__ Cv,
    int N, int K, int relu, int out_bf16)
{
  __shared__ unsigned short As[128*32];
  __shared__ unsigned short Bs[128*32];
  const int tid  = threadIdx.x;
  const int lane = tid & 63;
  const int wave = tid >> 6;

  // bijective chunked XCD swizzle (m204 form)
  const int gx  = gridDim.x;
  const int nwg = gx * gridDim.y;
  const int id  = blockIdx.y * gx + blockIdx.x;
  const int q = nwg >> 3, r = nwg & 7;
  const int xcd = id & 7, rank = id >> 3;
  const int nid = (xcd < r) ? (xcd*(q+1) + rank)
                            : (r*(q+1) + (xcd - r)*q + rank);
  const long long bm = (long long)(nid / gx) * 128;
  const int bn = (nid % gx) * 128;

  const int wm = (wave & 1) * 64;
  const int wn = (wave >> 1) * 64;
  // staging: lane i covers LDS slot (row = wave*32 + t*16 + i/4, colgroup = i%4)
  const int srow = lane >> 2;
  const int sg   = lane & 3;
  const int gcol = (sg ^ ((srow >> 1) & 3)) * 8;   // swizzled global col group
  const unsigned short* pa0 = A  + (bm + wave*32 + srow) * K + gcol;
  const unsigned short* pb0 = BT + (long long)(bn + wave*32 + srow) * K + gcol;
  unsigned short* lA0 = As + (wave*32     )*32;
  unsigned short* lA1 = As + (wave*32 + 16)*32;
  unsigned short* lB0 = Bs + (wave*32     )*32;
  unsigned short* lB1 = Bs + (wave*32 + 16)*32;

  const int lm = lane & 15;
  const int q2 = lane >> 4;
  const int fcol = ((q2 ^ ((lm >> 1) & 3)) * 8);   // swizzled LDS col group for frags

  f32x4 acc[4][4] = {};

  for (int k0 = 0; k0 < K; k0 += 32){
    __builtin_amdgcn_global_load_lds((const __attribute__((address_space(1))) void*)(pa0 + k0),
        (__attribute__((address_space(3))) void*)lA0, 16, 0, 0);
    __builtin_amdgcn_global_load_lds((const __attribute__((address_space(1))) void*)(pa0 + 16*K + k0),
        (__attribute__((address_space(3))) void*)lA1, 16, 0, 0);
    __builtin_amdgcn_global_load_lds((const __attribute__((address_space(1))) void*)(pb0 + k0),
        (__attribute__((address_space(3))) void*)lB0, 16, 0, 0);
    __builtin_amdgcn_global_load_lds((const __attribute__((address_space(1))) void*)(pb0 + 16*K + k0),
        (__attribute__((address_space(3))) void*)lB1, 16, 0, 0);
    __syncthreads();
    short8 af[4], bfr[4];
    #pragma unroll
    for (int i = 0; i < 4; i++){
      af[i]  = *(const short8*)&As[(wm + 16*i + lm)*32 + fcol];
      bfr[i] = *(const short8*)&Bs[(wn + 16*i + lm)*32 + fcol];
    }
    #pragma unroll
    for (int i = 0; i < 4; i++)
      #pragma unroll
      for (int j = 0; j < 4; j++)
        acc[i][j] = __builtin_amdgcn_mfma_f32_16x16x32_bf16(af[i], bfr[j], acc[i][j], 0, 0, 0);
    __syncthreads();
  }

  // epilogue: D[m = q2*4 + r (within 16-tile), n = lm]
  #pragma unroll
  for (int j = 0; j < 4; j++){
    int c = bn + wn + 16*j + lm;
    float bv = bias ? bias[c] : 0.f;
    #pragma unroll
    for (int i = 0; i < 4; i++){
      long long mrow = bm + wm + 16*i + q2*4;
      #pragma unroll
      for (int rr = 0; rr < 4; rr++){
        float v = acc[i][j][rr] + bv;
        if (relu) v = fmaxf(v, 0.f);
        if (out_bf16) ((unsigned short*)Cv)[(mrow + rr)*N + c] = f2bf(v);
        else          ((float*)Cv)[(mrow + rr)*N + c] = v;
      }
    }
  }
}

// ---------------- GCN aggregation (CSR gather, F=512, bf16 in/out) ----------------
// 2 rows per 256-thread block (128 lanes/row), uint2 (8B) H loads,
// edge loop unrolled x4 -> 4 independent gather chains in flight.
__global__ __launch_bounds__(256) void k_agg_bf(
    const unsigned short* __restrict__ H, const int* __restrict__ rowptr,
    const int* __restrict__ col, const float* __restrict__ w,
    const float* __restrict__ dinv, const float* __restrict__ bias,
    unsigned short* __restrict__ out, int nrows)
{
  const int half = threadIdx.x >> 7;            // 0 or 1
  const int t    = threadIdx.x & 127;
  const int row  = blockIdx.x*2 + half;
  if (row >= nrows) return;
  const int f = t * 4;
  const int beg = rowptr[row], end = rowptr[row+1];
  float a0 = 0.f, a1 = 0.f, a2 = 0.f, a3 = 0.f;
  int e = beg;
  for (; e + 3 < end; e += 4){
    int s0 = col[e], s1 = col[e+1], s2 = col[e+2], s3 = col[e+3];
    float w0 = w[e], w1 = w[e+1], w2 = w[e+2], w3 = w[e+3];
    uint2 h0 = *(const uint2*)&H[(size_t)s0*512 + f];
    uint2 h1 = *(const uint2*)&H[(size_t)s1*512 + f];
    uint2 h2 = *(const uint2*)&H[(size_t)s2*512 + f];
    uint2 h3 = *(const uint2*)&H[(size_t)s3*512 + f];
    a0 += w0*bf2f(h0.x & 0xffffu) + w1*bf2f(h1.x & 0xffffu)
        + w2*bf2f(h2.x & 0xffffu) + w3*bf2f(h3.x & 0xffffu);
    a1 += w0*bf2f(h0.x >> 16)     + w1*bf2f(h1.x >> 16)
        + w2*bf2f(h2.x >> 16)     + w3*bf2f(h3.x >> 16);
    a2 += w0*bf2f(h0.y & 0xffffu) + w1*bf2f(h1.y & 0xffffu)
        + w2*bf2f(h2.y & 0xffffu) + w3*bf2f(h3.y & 0xffffu);
    a3 += w0*bf2f(h0.y >> 16)     + w1*bf2f(h1.y >> 16)
        + w2*bf2f(h2.y >> 16)     + w3*bf2f(h3.y >> 16);
  }
  for (; e < end; ++e){
    int s = col[e]; float ws = w[e];
    uint2 h = *(const uint2*)&H[(size_t)s*512 + f];
    a0 += ws*bf2f(h.x & 0xffffu); a1 += ws*bf2f(h.x >> 16);
    a2 += ws*bf2f(h.y & 0xffffu); a3 += ws*bf2f(h.y >> 16);
  }
  float di = dinv[row];
  float sc = di*di;
  uint2 hs = *(const uint2*)&H[(size_t)row*512 + f];
  float4 bv = *(const float4*)&bias[f];
  float o0 = di*a0 + sc*bf2f(hs.x & 0xffffu) + bv.x;
  float o1 = di*a1 + sc*bf2f(hs.x >> 16)     + bv.y;
  float o2 = di*a2 + sc*bf2f(hs.y & 0xffffu) + bv.z;
  float o3 = di*a3 + sc*bf2f(hs.y >> 16)     + bv.w;
  uint2 o;
  o.x = (uint_t)f2bf(o0) | ((uint_t)f2bf(o1) << 16);
  o.y = (uint_t)f2bf(o2) | ((uint_t)f2bf(o3) << 16);
  *(uint2*)&out[(size_t)row*512 + f] = o;
}

// ---------------- cosine + sigmoid (bf16 in), one wave per row ----------------
__global__ __launch_bounds__(256) void k_cos_bf(const unsigned short* __restrict__ a,
    const unsigned short* __restrict__ b, float* __restrict__ out, int n)
{
  const int lane = threadIdx.x & 63;
  const int wid  = threadIdx.x >> 6;
  const int row  = blockIdx.x*4 + wid;
  if (row >= n) return;
  uint4 x = *(const uint4*)&a[(size_t)row*512 + lane*8];
  uint4 y = *(const uint4*)&b[(size_t)row*512 + lane*8];
  uint_t xs[4] = {x.x, x.y, x.z, x.w};
  uint_t ys[4] = {y.x, y.y, y.z, y.w};
  float dot = 0.f, na = 0.f, nb = 0.f;
  #pragma unroll
  for (int k = 0; k < 4; k++){
    float x0 = bf2f(xs[k] & 0xffffu), x1 = bf2f(xs[k] >> 16);
    float y0 = bf2f(ys[k] & 0xffffu), y1 = bf2f(ys[k] >> 16);
    dot += x0*y0 + x1*y1;
    na  += x0*x0 + x1*x1;
    nb  += y0*y0 + y1*y1;
  }
  #pragma unroll
  for (int off = 32; off; off >>= 1){
    dot += __shfl_down(dot, off);
    na  += __shfl_down(na , off);
    nb  += __shfl_down(nb , off);
  }
  if (lane == 0){
    float dn = fmaxf(sqrtf(na), 1e-8f);
    float tn = fmaxf(sqrtf(nb), 1e-8f);
    out[row] = 1.f/(1.f + expf(-dot/(dn*tn)));
  }
}

extern "C" void kernel_launch(void* const* d_in, const int* in_sizes, int n_in,
                              void* d_out, int out_size, void* d_ws, size_t ws_size,
                              hipStream_t stream)
{
  (void)in_sizes; (void)n_in; (void)out_size; (void)ws_size;
  const float* drug   = (const float*)d_in[0];   // [50000,2048]
  const float* target = (const float*)d_in[1];   // [50000,1024]
  const int*   ei_d   = (const int*)d_in[2];
  const int*   ei_t   = (const int*)d_in[3];
  const float* Wd = (const float*)d_in[4];       // [2048,1024]
  const float* bd = (const float*)d_in[5];
  const float* Wt = (const float*)d_in[6];       // [1024,1024]
  const float* bt = (const float*)d_in[7];
  const float* W1 = (const float*)d_in[8];       // [1024,512]
  const float* b1 = (const float*)d_in[9];
  const float* W2 = (const float*)d_in[10];      // [512,512]
  const float* b2 = (const float*)d_in[11];
  float* out = (float*)d_out;

  const int n = NNODES, E = NEDGES;
  char* ws = (char*)d_ws;
  size_t off = 0;
  auto alloc = [&](size_t bytes)->char* {
    char* p = ws + off; off += (bytes + 255) & ~(size_t)255; return p;
  };
  int*   cnt_d  = (int*)  alloc((size_t)n*4);
  int*   cnt_t  = (int*)  alloc((size_t)n*4);
  int*   rp_d   = (int*)  alloc((size_t)(n+1)*4);
  int*   rp_t   = (int*)  alloc((size_t)(n+1)*4);
  int*   cur_d  = (int*)  alloc((size_t)n*4);
  int*   cur_t  = (int*)  alloc((size_t)n*4);
  int*   col_d  = (int*)  alloc((size_t)E*4);
  int*   col_t  = (int*)  alloc((size_t)E*4);
  float* w_d    = (float*)alloc((size_t)E*4);
  float* w_t    = (float*)alloc((size_t)E*4);
  float* dinv_d = (float*)alloc((size_t)n*4);
  float* dinv_t = (float*)alloc((size_t)n*4);
  int*   bsum   = (int*)  alloc(128*4);
  unsigned short* WdT = (unsigned short*)alloc((size_t)1024*2048*2);
  unsigned short* WtT = (unsigned short*)alloc((size_t)1024*1024*2);
  unsigned short* W1T = (unsigned short*)alloc((size_t)512*1024*2);
  unsigned short* W2T = (unsigned short*)alloc((size_t)512*512*2);
  // big buffers (aliased):
  //   bufA [MP,2048]  : cast staging (drug then target); later reused as dp2 [2MP,512]
  //   bufP [2MP,1024] : projector outputs (drug rows 0..MP, target MP..2MP); later dp1 [2MP,512]
  //   bufH [2MP,512]  : GEMM outputs feeding aggregation
  unsigned short* bufA = (unsigned short*)alloc((size_t)MP*2048*2);
  unsigned short* bufP = (unsigned short*)alloc((size_t)2*MP*1024*2);
  unsigned short* bufH = (unsigned short*)alloc((size_t)2*MP*512*2);
  unsigned short* dp1 = bufP;   // [2MP,512] — bufP dead after W1 GEMM
  unsigned short* dp2 = bufA;   // [2MP,512] — bufA dead after projectors

  dim3 blk(256);
  const int NB = (n + 1023)/1024;   // 49 scan blocks per graph

  // ---- CSR build ----
  k_init_counts<<<(n+255)/256, blk, 0, stream>>>(cnt_d, cnt_t, n);
  k_count<<<(E+255)/256, blk, 0, stream>>>(ei_d, cnt_d, E);
  k_count<<<(E+255)/256, blk, 0, stream>>>(ei_t, cnt_t, E);
  k_scan_blk<<<dim3(NB,2), 1024, 0, stream>>>(cnt_d, cnt_t, rp_d, rp_t, dinv_d, dinv_t, bsum, n);
  k_scan_bsum<<<1, 128, 0, stream>>>(bsum, rp_d, rp_t, NB, n);
  k_scan_add<<<dim3(NB,2), 1024, 0, stream>>>(bsum, rp_d, rp_t, cur_d, cur_t, n);
  k_fill<<<(E+255)/256, blk, 0, stream>>>(ei_d, cur_d, col_d, w_d, dinv_d, E);
  k_fill<<<(E+255)/256, blk, 0, stream>>>(ei_t, cur_t, col_t, w_t, dinv_t, E);

  // ---- weights: transpose + cast ----
  k_tr_cast<<<dim3(1024/32, 2048/32), blk, 0, stream>>>(Wd, WdT, 2048, 1024);
  k_tr_cast<<<dim3(1024/32, 1024/32), blk, 0, stream>>>(Wt, WtT, 1024, 1024);
  k_tr_cast<<<dim3( 512/32, 1024/32), blk, 0, stream>>>(W1, W1T, 1024,  512);
  k_tr_cast<<<dim3( 512/32,  512/32), blk, 0, stream>>>(W2, W2T,  512,  512);

  // ---- projectors (drug then target; target reuses bufA after drug GEMM) ----
  {
    long long nsrc = (long long)n*2048, ntot = (long long)MP*2048;
    k_cast_bf<<<(unsigned)((ntot/4 + 255)/256), blk, 0, stream>>>(drug, bufA, nsrc, ntot);
  }
  gemm_bf16<<<dim3(8, MP/128), blk, 0, stream>>>(bufA, WdT, bd, bufP, 1024, 2048, 1, 1);
  {
    long long nsrc = (long long)n*1024, ntot = (long long)MP*1024;
    k_cast_bf<<<(unsigned)((ntot/4 + 255)/256), blk, 0, stream>>>(target, bufA, nsrc, ntot);
  }
  gemm_bf16<<<dim3(8, MP/128), blk, 0, stream>>>(bufA, WtT, bt, bufP + (size_t)MP*1024, 1024, 1024, 1, 1);

  // ---- GCN layer 1 (batched GEMM over both graphs' rows) ----
  gemm_bf16<<<dim3(4, (2*MP)/128), blk, 0, stream>>>(bufP, W1T, nullptr, bufH, 512, 1024, 0, 1);
  k_agg_bf<<<(n+1)/2, blk, 0, stream>>>(bufH, rp_d, col_d, w_d, dinv_d, b1, dp1, n);
  k_agg_bf<<<(n+1)/2, blk, 0, stream>>>(bufH + (size_t)MP*512, rp_t, col_t, w_t, dinv_t, b1,
                                        dp1 + (size_t)MP*512, n);

  // ---- GCN layer 2 ----
  gemm_bf16<<<dim3(4, (2*MP)/128), blk, 0, stream>>>(dp1, W2T, nullptr, bufH, 512, 512, 0, 1);
  k_agg_bf<<<(n+1)/2, blk, 0, stream>>>(bufH, rp_d, col_d, w_d, dinv_d, b2, dp2, n);
  k_agg_bf<<<(n+1)/2, blk, 0, stream>>>(bufH + (size_t)MP*512, rp_t, col_t, w_t, dinv_t, b2,
                                        dp2 + (size_t)MP*512, n);

  // ---- cosine + sigmoid ----
  k_cos_bf<<<(n+3)/4, blk, 0, stream>>>(dp2, dp2 + (size_t)MP*512, out, n);
}